// Round 4
// baseline (397.599 us; speedup 1.0000x reference)
//
#include <hip/hip_runtime.h>

// SO3Linear: out[b,m,o] = sum_i x[b,m,i] * (W[l(m),o,i] - 1/sqrt(128)), bias on m=0.
// v5: degree-grouped, barrier-free. Key facts: (1) m-slices with the same l share
// one weight matrix; (2) for fixed b those slices are CONTIGUOUS in memory. So a
// block owns one l and processes tiles of 16 consecutive (b,m) rows -- rows in a
// tile are 512B-strided neighbors, so direct fragment loads (128B granule) and
// direct swapped-operand stores (full 64B lines) are clean WITHOUT any x/out LDS
// staging and WITHOUT main-loop barriers (v4 spent ~100us of 147 stalled in its
// barrier-lockstep phases at 2 blocks/CU). LDS = W only (32KB, full 4-bit XOR
// swizzle: v4's 3-bit key still had 8-way slot aliasing -> 4.1M conflict cycles).
// 3 blocks/CU, 12 free-running waves, 4 tiles/wave, double-buffered prefetch.
// Grid: 1600 l-homogeneous blocks (64,192,320,448,576 for l=0..4); 2l+1 division
// is a compile-time magic-mul via templates. l=0: every row is m=0 -> uniform bias.

#define NF 128
#define NUM_M 25
#define ROWSTRIDE (NUM_M * NF)   // 3200 floats per batch row

typedef __attribute__((ext_vector_type(8))) short short8;   // 8 bf16 (4 VGPRs)
typedef __attribute__((ext_vector_type(4))) float floatx4;  // 16 B ld/st, MFMA C/D

// fp32 -> bf16, round-to-nearest-even (inputs finite; no NaN handling needed)
__device__ inline short f2bf(float f) {
    union { float f; unsigned u; } v;
    v.f = f;
    unsigned r = v.u + 0x7fffu + ((v.u >> 16) & 1u);
    return (short)(r >> 16);
}

// Issue the 8 global loads for one 16-row tile (lane n16 <-> row, q <-> k-chunk).
template<int L>
__device__ __forceinline__ void issue_tile(const float* __restrict__ x,
                                           int tile, int n16, int q,
                                           floatx4 (&raw)[8], int& rowoff) {
    constexpr int G  = 2 * L + 1;
    constexpr int M0 = L * L;
    const int bm = tile * 16 + n16;     // row index within this l-group
    const int b  = bm / G;              // G compile-time -> magic multiply
    const int r  = bm - b * G;
    rowoff = b * ROWSTRIDE + (M0 + r) * NF;
    const float* xp = x + rowoff + q * 8;
    #pragma unroll
    for (int kc = 0; kc < 4; ++kc) {
        raw[2 * kc]     = *(const floatx4*)(xp + kc * 32);
        raw[2 * kc + 1] = *(const floatx4*)(xp + kc * 32 + 4);
    }
}

template<int L>
__device__ __forceinline__ void so3_run(int lblk,
                                        const float* __restrict__ x,
                                        const float* __restrict__ w,
                                        const float* __restrict__ bias,
                                        float* __restrict__ out,
                                        short* wlds, float* blds) {
    const int tid  = threadIdx.x;
    const int wave = tid >> 6;
    const int lane = tid & 63;
    const int q    = lane >> 4;   // 0..3
    const int n16  = lane & 15;   // 0..15
    const float bound = 0.08838834764831843f; // 1/sqrt(128)

    const int tbase = lblk * 16 + wave * 4;   // wave's 4 consecutive tiles

    // ---- tile-0 loads first: in flight during the whole W prologue ----
    floatx4 rawA[8], rawB[8];
    int offA = 0, offB = 0;
    issue_tile<L>(x, tbase + 0, n16, q, rawA, offA);
    __builtin_amdgcn_sched_barrier(0);   // keep these above the W loads

    // ---- W[L] fp32 -> centered bf16 -> XOR-swizzled LDS (once per block) ----
    // chunk c (16B) of row o lives at byte o*256 + (c*16 ^ ((o&15)<<4)).
    // Full 4-bit key: both prologue writes and fragment reads spread to the
    // optimal 4 lanes per 16B slot (v4's 3-bit key aliased 8 ways).
    {
        const int o    = tid >> 1;
        const int half = tid & 1;
        const float* wr = w + L * NF * NF + o * NF + half * 64;
        char* wbp = (char*)wlds;
        #pragma unroll
        for (int jj = 0; jj < 8; ++jj) {
            floatx4 f0 = ((const floatx4*)wr)[2 * jj];
            floatx4 f1 = ((const floatx4*)wr)[2 * jj + 1];
            short8 s;
            s[0] = f2bf(f0[0] - bound); s[1] = f2bf(f0[1] - bound);
            s[2] = f2bf(f0[2] - bound); s[3] = f2bf(f0[3] - bound);
            s[4] = f2bf(f1[0] - bound); s[5] = f2bf(f1[1] - bound);
            s[6] = f2bf(f1[2] - bound); s[7] = f2bf(f1[3] - bound);
            const int c = half * 8 + jj;
            *(short8*)(wbp + o * 256 + ((c * 16) ^ ((o & 15) << 4))) = s;
        }
        if (L == 0 && tid < NF) blds[tid] = bias[tid];  // l=0: all rows get bias
    }
    __syncthreads();   // the ONLY barrier; waves run free after this

    const char* wbp = (const char*)wlds;
    int lr[4];
    #pragma unroll
    for (int kc = 0; kc < 4; ++kc)
        lr[kc] = n16 * 256 + ((kc * 64 + q * 16) ^ (n16 << 4));

    #pragma unroll
    for (int t = 0; t < 4; ++t) {
        floatx4* cur = (t & 1) ? rawB : rawA;        // folds: t is literal
        const int rowoff = (t & 1) ? offB : offA;

        // prefetch next tile into the other buffer; pin issue order so the
        // loads get the full convert+MFMA+store phase to land
        if (t < 3) {
            if (t & 1) issue_tile<L>(x, tbase + t + 1, n16, q, rawA, offA);
            else       issue_tile<L>(x, tbase + t + 1, n16, q, rawB, offB);
            __builtin_amdgcn_sched_barrier(0);
        }

        // ---- convert current tile to A fragments (waits vmcnt for cur only) ----
        short8 afrag[4];
        #pragma unroll
        for (int kc = 0; kc < 4; ++kc) {
            floatx4 x0 = cur[2 * kc], x1 = cur[2 * kc + 1];
            short8 f;
            f[0] = f2bf(x0[0]); f[1] = f2bf(x0[1]);
            f[2] = f2bf(x0[2]); f[3] = f2bf(x0[3]);
            f[4] = f2bf(x1[0]); f[5] = f2bf(x1[1]);
            f[6] = f2bf(x1[2]); f[7] = f2bf(x1[3]);
            afrag[kc] = f;
        }

        // ---- MFMA, swapped operands: D[o][bm] ----
        floatx4 acc[8] = {};
        #pragma unroll
        for (int kc = 0; kc < 4; ++kc) {
            short8 wt[8];
            #pragma unroll
            for (int nt = 0; nt < 8; ++nt)
                wt[nt] = *(const short8*)(wbp + lr[kc] + nt * 4096);
            #pragma unroll
            for (int nt = 0; nt < 8; ++nt)
                acc[nt] = __builtin_amdgcn_mfma_f32_16x16x32_bf16(
                    wt[nt], afrag[kc], acc[nt], 0, 0, 0);
        }

        // ---- store: lane's 4 values = o in [nt*16+q*4, +4) of its own row;
        //      rows are 512B-strided neighbors -> full 64B lines per instr ----
        float* op = out + rowoff + q * 4;
        #pragma unroll
        for (int nt = 0; nt < 8; ++nt) {
            floatx4 v = acc[nt];
            if (L == 0) {
                const floatx4 bv = *(const floatx4*)(blds + nt * 16 + q * 4);
                v[0] += bv[0]; v[1] += bv[1]; v[2] += bv[2]; v[3] += bv[3];
            }
            __builtin_nontemporal_store(v, (floatx4*)(op + nt * 16));
        }
    }
}

__global__ __launch_bounds__(256, 3)
void so3_kernel(const float* __restrict__ x,
                const float* __restrict__ w,
                const float* __restrict__ bias,
                float* __restrict__ out) {
    __shared__ short wlds[NF * NF];   // 32 KB: W[l] bf16, swizzled
    __shared__ float blds[NF];        // bias copy (l=0 path only)
    const int bx = blockIdx.x;
    // blocks per l = 64*(2l+1): tiles per l = 1024*(2l+1) = 16384*(2l+1)/16 rows
    if      (bx <   64) so3_run<0>(bx,        x, w, bias, out, wlds, blds);
    else if (bx <  256) so3_run<1>(bx -   64, x, w, bias, out, wlds, blds);
    else if (bx <  576) so3_run<2>(bx -  256, x, w, bias, out, wlds, blds);
    else if (bx < 1024) so3_run<3>(bx -  576, x, w, bias, out, wlds, blds);
    else                so3_run<4>(bx - 1024, x, w, bias, out, wlds, blds);
}

extern "C" void kernel_launch(void* const* d_in, const int* in_sizes, int n_in,
                              void* d_out, int out_size, void* d_ws, size_t ws_size,
                              hipStream_t stream) {
    const float* x    = (const float*)d_in[0]; // [16384, 25, 128]
    const float* w    = (const float*)d_in[1]; // [5, 128, 128]
    const float* bias = (const float*)d_in[2]; // [128]
    float* out = (float*)d_out;                // [16384, 25, 128]

    dim3 grid(1600);
    dim3 block(256);
    so3_kernel<<<grid, block, 0, stream>>>(x, w, bias, out);
}